// Round 6
// baseline (62.063 us; speedup 1.0000x reference)
//
#include <hip/hip_runtime.h>

// GaussianMask: K[b,c,k,h,w] = exp(-(Xnbr - Xctr)^2 / 2), bw=1
// X: (4,3,512,512) fp32. Out: (4,3,24,512,512) fp32. Zero padding, center skipped.
// Write-BW-bound: 302 MB out vs 12.6 MB in.
// R6: k = blockIdx.y (compile-time dr,dc) as R5, PLUS 4 quads per thread
//     (strip-mined 512 quads apart): every store is a coalesced 1KB wave-write,
//     each block writes 32KB contiguous, wave count 73.7K (9x device capacity),
//     per-wave store volume 4KB (amortizes wave setup 4x vs R5's 1KB).

#define HH 512
#define WW 512
#define NPLANES 12   // B*C
#define NK 24
#define HW (HH * WW)

typedef float f32x4 __attribute__((ext_vector_type(4)));

extern "C" __device__ float __builtin_amdgcn_exp2f(float);

template <int DR, int DC>
__device__ __forceinline__ f32x4 compute_quad(const float* __restrict__ Xp,
                                              int h, int w0)
{
    const float c = -0.5f * 1.44269504088896340736f;  // -0.5*log2(e)
    const f32x4 xc = *reinterpret_cast<const f32x4*>(Xp + (size_t)h * WW + w0);

    const int hh = h + DR - 2;
    f32x4 nb;
    if (hh >= 0 && hh < HH) {                    // wave-uniform (64 lanes share h)
        const float* nr = Xp + (size_t)hh * WW;
        if constexpr (DC == 2) {
            nb = *reinterpret_cast<const f32x4*>(nr + w0);
        } else if constexpr (DC < 2) {
            const f32x4 qC = *reinterpret_cast<const f32x4*>(nr + w0);
            const f32x4 qA = *reinterpret_cast<const f32x4*>(nr + (w0 > 0 ? w0 - 4 : 0));
            constexpr int off = DC - 2;          // -2 or -1
            #pragma unroll
            for (int i = 0; i < 4; ++i) {
                float v;
                if (off + i < 0) {               // compile-time per i
                    v = (w0 > 0) ? qA[4 + off + i] : 0.0f;
                } else {
                    v = qC[off + i];
                }
                nb[i] = v;
            }
        } else {                                 // DC > 2
            const f32x4 qC = *reinterpret_cast<const f32x4*>(nr + w0);
            const f32x4 qB = *reinterpret_cast<const f32x4*>(nr + (w0 < WW - 4 ? w0 + 4 : WW - 4));
            constexpr int off = DC - 2;          // 1 or 2
            #pragma unroll
            for (int i = 0; i < 4; ++i) {
                float v;
                if (off + i > 3) {               // compile-time per i
                    v = (w0 < WW - 4) ? qB[off + i - 4] : 0.0f;
                } else {
                    v = qC[off + i];
                }
                nb[i] = v;
            }
        }
    } else {
        #pragma unroll
        for (int i = 0; i < 4; ++i) nb[i] = 0.0f;   // zero padding row
    }

    f32x4 v;
    #pragma unroll
    for (int i = 0; i < 4; ++i) {
        const float d = nb[i] - xc[i];
        v[i] = __builtin_amdgcn_exp2f(d * d * c);
    }
    return v;
}

template <int DR, int DC>
__device__ __forceinline__ void body(const float* __restrict__ Xp,
                                     float* __restrict__ kp,
                                     int rembase, int tid)
{
    #pragma unroll
    for (int s = 0; s < 4; ++s) {
        const int rem = rembase + s * 512 + tid;   // quad index within plane
        const int h   = rem >> 7;
        const int w0  = (rem & 127) << 2;
        const f32x4 v = compute_quad<DR, DC>(Xp, h, w0);
        __builtin_nontemporal_store(v, reinterpret_cast<f32x4*>(kp + (size_t)h * WW + w0));
    }
}

__global__ __launch_bounds__(512) void gauss_mask_kernel(
    const float* __restrict__ X, float* __restrict__ out)
{
    // blockIdx.x: 384 blocks, each covers 2048 consecutive quads (32 blocks/plane
    // exactly, so p is block-uniform). blockIdx.y = k (compile-time dr,dc).
    const int tid  = threadIdx.x;
    const int base = blockIdx.x * 2048;       // flat quad index [0, 786432)
    const int p    = base >> 16;              // 65536 quads per plane
    const int rembase = base & 65535;
    const int k    = blockIdx.y;

    const float* Xp = X + (size_t)p * HW;
    float* kp = out + ((size_t)p * NK + k) * HW;

    switch (k) {
        case  0: body<0, 0>(Xp, kp, rembase, tid); break;
        case  1: body<0, 1>(Xp, kp, rembase, tid); break;
        case  2: body<0, 2>(Xp, kp, rembase, tid); break;
        case  3: body<0, 3>(Xp, kp, rembase, tid); break;
        case  4: body<0, 4>(Xp, kp, rembase, tid); break;
        case  5: body<1, 0>(Xp, kp, rembase, tid); break;
        case  6: body<1, 1>(Xp, kp, rembase, tid); break;
        case  7: body<1, 2>(Xp, kp, rembase, tid); break;
        case  8: body<1, 3>(Xp, kp, rembase, tid); break;
        case  9: body<1, 4>(Xp, kp, rembase, tid); break;
        case 10: body<2, 0>(Xp, kp, rembase, tid); break;
        case 11: body<2, 1>(Xp, kp, rembase, tid); break;
        case 12: body<2, 3>(Xp, kp, rembase, tid); break;
        case 13: body<2, 4>(Xp, kp, rembase, tid); break;
        case 14: body<3, 0>(Xp, kp, rembase, tid); break;
        case 15: body<3, 1>(Xp, kp, rembase, tid); break;
        case 16: body<3, 2>(Xp, kp, rembase, tid); break;
        case 17: body<3, 3>(Xp, kp, rembase, tid); break;
        case 18: body<3, 4>(Xp, kp, rembase, tid); break;
        case 19: body<4, 0>(Xp, kp, rembase, tid); break;
        case 20: body<4, 1>(Xp, kp, rembase, tid); break;
        case 21: body<4, 2>(Xp, kp, rembase, tid); break;
        case 22: body<4, 3>(Xp, kp, rembase, tid); break;
        case 23: body<4, 4>(Xp, kp, rembase, tid); break;
    }
}

extern "C" void kernel_launch(void* const* d_in, const int* in_sizes, int n_in,
                              void* d_out, int out_size, void* d_ws, size_t ws_size,
                              hipStream_t stream) {
    const float* X = (const float*)d_in[0];
    float* out = (float*)d_out;

    // per k: 786432 quads / (512 threads * 4 quads) = 384 blocks
    dim3 grid(384, NK);
    gauss_mask_kernel<<<grid, 512, 0, stream>>>(X, out);
}

// Round 7
// 57.698 us; speedup vs baseline: 1.0757x; 1.0757x over previous
//
#include <hip/hip_runtime.h>

// GaussianMask: K[b,c,k,h,w] = exp(-(Xnbr - Xctr)^2 / 2), bw=1
// X: (4,3,512,512) fp32. Out: (4,3,24,512,512) fp32. Zero padding, center skipped.
// Write-BW-bound: 302 MB out vs 12.6 MB in.
// R7: block specializes DR = blockIdx.y (5 row-offsets). One neighbor-row read
//     (qA,qC,qB aligned f32x4) serves all 5 dc shifts via register selects:
//     <=4 wave-loads per 5KB written (L1 ratio 0.34 vs R5's 1.26), 1 quad/thread,
//     5-way store interleave (R3->R5 showed 24-way costs only ~2us).

#define HH 512
#define WW 512
#define NK 24
#define HW (HH * WW)

typedef float f32x4 __attribute__((ext_vector_type(4)));

extern "C" __device__ float __builtin_amdgcn_exp2f(float);

template <int DR>
__device__ __forceinline__ void body(const float* __restrict__ Xp,
                                     float* __restrict__ outp,  // + p*NK*HW + h*WW + w0
                                     int h, int w0)
{
    const float c = -0.5f * 1.44269504088896340736f;  // -0.5*log2(e)
    const f32x4 xc = *reinterpret_cast<const f32x4*>(Xp + (size_t)h * WW + w0);

    const int hh = h + DR - 2;
    const bool wl = (w0 > 0);
    const bool wr = (w0 < WW - 4);
    const bool rok = (DR == 2) || (hh >= 0 && hh < HH);  // wave-uniform (h uniform per wave)

    f32x4 qA, qC, qB;
    if (rok) {
        const float* nr = Xp + (size_t)hh * WW;
        qC = (DR == 2) ? xc : *reinterpret_cast<const f32x4*>(nr + w0);
        qA = *reinterpret_cast<const f32x4*>(nr + (wl ? w0 - 4 : 0));
        qB = *reinterpret_cast<const f32x4*>(nr + (wr ? w0 + 4 : WW - 4));
    } else {
        qA = (f32x4){0.f, 0.f, 0.f, 0.f};
        qC = (f32x4){0.f, 0.f, 0.f, 0.f};
        qB = (f32x4){0.f, 0.f, 0.f, 0.f};
    }

    // halo elements with zero-padding at w borders
    const float A2 = wl ? qA[2] : 0.f;
    const float A3 = wl ? qA[3] : 0.f;
    const float B0 = wr ? qB[0] : 0.f;
    const float B1 = wr ? qB[1] : 0.f;

    // shifted neighbor vectors for dc = 0..4 (all compile-time indexed after unroll)
    const float nb[5][4] = {
        {A2,    A3,    qC[0], qC[1]},
        {A3,    qC[0], qC[1], qC[2]},
        {qC[0], qC[1], qC[2], qC[3]},
        {qC[1], qC[2], qC[3], B0   },
        {qC[2], qC[3], B0,    B1   },
    };

    #pragma unroll
    for (int dc = 0; dc < 5; ++dc) {
        if (DR == 2 && dc == 2) continue;          // center tap skipped
        const int idx   = DR * 5 + dc;
        const int out_k = (idx < 12) ? idx : idx - 1;
        f32x4 v;
        #pragma unroll
        for (int i = 0; i < 4; ++i) {
            const float d = nb[dc][i] - xc[i];
            v[i] = __builtin_amdgcn_exp2f(d * d * c);
        }
        __builtin_nontemporal_store(v, reinterpret_cast<f32x4*>(outp + (size_t)out_k * HW));
    }
}

__global__ __launch_bounds__(512) void gauss_mask_kernel(
    const float* __restrict__ X, float* __restrict__ out)
{
    // blockIdx.x covers all (p,h,w0) quads once; blockIdx.y = DR (row offset group)
    const int idx = blockIdx.x * 512 + threadIdx.x;  // [0, 786432)
    const int p   = idx >> 16;            // 65536 quads per plane
    const int rem = idx & 65535;
    const int h   = rem >> 7;             // wave covers half a row -> h wave-uniform
    const int w0  = (rem & 127) << 2;

    const float* Xp = X + (size_t)p * HW;
    float* outp = out + (size_t)p * NK * HW + (size_t)h * WW + w0;

    switch (blockIdx.y) {
        case 0: body<0>(Xp, outp, h, w0); break;
        case 1: body<1>(Xp, outp, h, w0); break;
        case 2: body<2>(Xp, outp, h, w0); break;
        case 3: body<3>(Xp, outp, h, w0); break;
        case 4: body<4>(Xp, outp, h, w0); break;
    }
}

extern "C" void kernel_launch(void* const* d_in, const int* in_sizes, int n_in,
                              void* d_out, int out_size, void* d_ws, size_t ws_size,
                              hipStream_t stream) {
    const float* X = (const float*)d_in[0];
    float* out = (float*)d_out;

    // 786432 quads / 512 threads = 1536 blocks per DR group; 5 DR groups
    dim3 grid(1536, 5);
    gauss_mask_kernel<<<grid, 512, 0, stream>>>(X, out);
}